// Round 2
// baseline (277.466 us; speedup 1.0000x reference)
//
#include <hip/hip_runtime.h>

// Problem constants (match reference)
#define BB 4096
#define DD 8192
#define KK 5
#define GS 40
#define MAXIT 3
#define EFF 17              // 4*(KK-1)+1 composed taps
#define DF4 (DD/4)          // 2048 f4 per row
#define EPAD 20             // padded per-row composed-kernel stride (floats, 5 f4)
#define WS_OFF 64           // float offset of E table inside ws (keeps ws[0] free)

typedef float vf4 __attribute__((ext_vector_type(4)));

__device__ __forceinline__ int iabs(int a) { return a < 0 ? -a : a; }

// Compose e (length LEN) with a 5-tap kernel -> length LEN+4.
// LEN is a template parameter: all indices compile-time constant -> stays in VGPRs.
template<int LEN>
__device__ __forceinline__ void compose5(float* e, const float* k5) {
    float ne[LEN + KK - 1];
#pragma unroll
    for (int m = 0; m < LEN + KK - 1; ++m) ne[m] = 0.f;
#pragma unroll
    for (int m = 0; m < LEN; ++m)
#pragma unroll
        for (int j = 0; j < KK; ++j) ne[m + j] += e[m] * k5[j];
#pragma unroll
    for (int m = 0; m < LEN + KK - 1; ++m) e[m] = ne[m];
}

__device__ __forceinline__ void pick5(int i, int iters, int max_it,
                                      const float* maxk, const float* idk,
                                      float* k5) {
#pragma unroll
    for (int j = 0; j < KK; ++j)
        k5[j] = (i < iters) ? maxk[j]
              : ((i < max_it) ? idk[j] : ((j == (KK - 1) / 2) ? 1.f : 0.f));
}

// ---------------------------------------------------------------------------
// Kernel A (16 blocks x 256): batch max + per-row composed 17-tap kernel.
// Unchanged from previous round (verified). Writes E[4096][20] to ws.
// ---------------------------------------------------------------------------
__global__ __launch_bounds__(256) void k_compose(const int* __restrict__ g,
                                                 const float* __restrict__ kernels,
                                                 float* __restrict__ wsE) {
    __shared__ int red[256];
    const int t = threadIdx.x;

    const int4* g4 = (const int4*)g;
    int m = 0;
    for (int i = t; i < BB / 4; i += 256) {
        int4 v = g4[i];
        m = max(m, max(max(iabs(v.x), iabs(v.y)), max(iabs(v.z), iabs(v.w))));
    }
    red[t] = m;
    __syncthreads();
    for (int s = 128; s > 0; s >>= 1) {
        if (t < s) red[t] = max(red[t], red[t + s]);
        __syncthreads();
    }
    const int max_it = red[0] / GS;

    const int r  = blockIdx.x * 256 + t;     // row, 16*256 = 4096
    const int gv = g[r];
    const int sign  = gv > 0 ? 1 : (gv < 0 ? -1 : 0);
    const int a     = iabs(gv);
    const int iters = a / GS;
    const int rem   = a % GS;

    const float* mk = kernels + (size_t)(sign * GS + GS) * KK;
    const float* ik = kernels + (size_t)GS * KK;
    const float* fk = kernels + (size_t)(rem * sign + GS) * KK;
    float maxk[KK], idk[KK], fink[KK];
#pragma unroll
    for (int j = 0; j < KK; ++j) { maxk[j] = mk[j]; idk[j] = ik[j]; fink[j] = fk[j]; }

    float e[EPAD];
#pragma unroll
    for (int q = 0; q < EPAD; ++q) e[q] = 0.f;
    e[0] = 1.f;

    float k5[KK];
    pick5(0, iters, max_it, maxk, idk, k5); compose5<1>(e, k5);
    pick5(1, iters, max_it, maxk, idk, k5); compose5<5>(e, k5);
    pick5(2, iters, max_it, maxk, idk, k5); compose5<9>(e, k5);
    compose5<13>(e, fink);                   // e[0..16] final, e[17..19] = 0

    vf4* dst = (vf4*)(wsE + (size_t)r * EPAD);
    vf4 o0; o0.x = e[0];  o0.y = e[1];  o0.z = e[2];  o0.w = e[3];
    vf4 o1; o1.x = e[4];  o1.y = e[5];  o1.z = e[6];  o1.w = e[7];
    vf4 o2; o2.x = e[8];  o2.y = e[9];  o2.z = e[10]; o2.w = e[11];
    vf4 o3; o3.x = e[12]; o3.y = e[13]; o3.z = e[14]; o3.w = e[15];
    vf4 o4; o4.x = e[16]; o4.y = e[17]; o4.z = e[18]; o4.w = e[19];
    dst[0] = o0; dst[1] = o1; dst[2] = o2; dst[3] = o3; dst[4] = o4;
}

// ---------------------------------------------------------------------------
// Kernel B (DISCRIMINATOR REWRITE): no LDS, no barrier, no NT stores, no halo
// special-casing. One block per row (4096 blocks x 256 threads), 8 f4 outputs
// per thread. Each f4 output reads 5 overlapping coalesced f4 loads; the 4/5
// overlap between neighboring lanes is served by L1/L2, HBM traffic stays 1x.
// Circular wrap via (v-2+q) & (DF4-1) at f4 granularity (row len % 4 == 0).
// ---------------------------------------------------------------------------
__global__ __launch_bounds__(256) void k_conv_direct(const float* __restrict__ x,
                                                     const float* __restrict__ wsE,
                                                     float* __restrict__ out) {
    const int b = blockIdx.x;                // row
    const int t = threadIdx.x;

    // block-uniform composed kernel: 5 f4 loads, L2-hot
    const float4* ev = (const float4*)(wsE + (size_t)b * EPAD);
    float4 e0 = ev[0], e1 = ev[1], e2 = ev[2], e3 = ev[3], e4 = ev[4];
    float e[EFF] = { e0.x, e0.y, e0.z, e0.w,
                     e1.x, e1.y, e1.z, e1.w,
                     e2.x, e2.y, e2.z, e2.w,
                     e3.x, e3.y, e3.z, e3.w,
                     e4.x };

    const float4* xr   = (const float4*)(x + (size_t)b * DD);
    float4*       outr = (float4*)(out + (size_t)b * DD);

#pragma unroll 2
    for (int k = 0; k < 8; ++k) {
        const int v = k * 256 + t;           // f4 idx within row [0, 2048)
        float f[EFF + 3];                    // x[4v-8 .. 4v+11]
#pragma unroll
        for (int q = 0; q < 5; ++q) {
            float4 val = xr[(v - 2 + q) & (DF4 - 1)];
            f[q * 4 + 0] = val.x; f[q * 4 + 1] = val.y;
            f[q * 4 + 2] = val.z; f[q * 4 + 3] = val.w;
        }
        float oc[4];
#pragma unroll
        for (int c = 0; c < 4; ++c) {
            float s = 0.f;
#pragma unroll
            for (int m = 0; m < EFF; ++m) s += e[m] * f[c + m];
            oc[c] = s;
        }
        float4 o;
        o.x = oc[0]; o.y = oc[1]; o.z = oc[2]; o.w = oc[3];
        outr[v] = o;                         // plain store (NT dropped on purpose)
    }
}

// ---------------------------------------------------------------------------
// Fallback path (ws too small): original verified single-pass kernels.
// ---------------------------------------------------------------------------
__global__ __launch_bounds__(256) void k_max_it(const int* __restrict__ g,
                                                int* __restrict__ ws) {
    __shared__ int red[256];
    int t = threadIdx.x;
    int m = 0;
    for (int i = t; i < BB; i += 256) m = max(m, iabs(g[i]));
    red[t] = m;
    __syncthreads();
    for (int s = 128; s > 0; s >>= 1) {
        if (t < s) red[t] = max(red[t], red[t + s]);
        __syncthreads();
    }
    if (t == 0) ws[0] = red[0] / GS;
}

__global__ __launch_bounds__(256) void k_conv_fb(const float* __restrict__ x,
                                                 const int* __restrict__ g,
                                                 const float* __restrict__ kernels,
                                                 const int* __restrict__ ws,
                                                 float* __restrict__ out) {
    const int b = blockIdx.x;
    const int t = threadIdx.x;

    const int gv    = g[b];
    const int sign  = gv > 0 ? 1 : (gv < 0 ? -1 : 0);
    const int a     = iabs(gv);
    const int iters = a / GS;
    const int rem   = a % GS;
    const int max_it = ws[0];

    float maxk[KK], idk[KK], fink[KK];
    const float* mk = kernels + (size_t)(sign * GS + GS) * KK;
    const float* ik = kernels + (size_t)GS * KK;
    const float* fk = kernels + (size_t)(rem * sign + GS) * KK;
#pragma unroll
    for (int j = 0; j < KK; ++j) { maxk[j] = mk[j]; idk[j] = ik[j]; fink[j] = fk[j]; }

    float e[EPAD];
#pragma unroll
    for (int q = 0; q < EPAD; ++q) e[q] = 0.f;
    e[0] = 1.f;
    float k5[KK];
    pick5(0, iters, max_it, maxk, idk, k5); compose5<1>(e, k5);
    pick5(1, iters, max_it, maxk, idk, k5); compose5<5>(e, k5);
    pick5(2, iters, max_it, maxk, idk, k5); compose5<9>(e, k5);
    compose5<13>(e, fink);

    const float4* xr   = (const float4*)(x + (size_t)b * DD);
    float4*       outr = (float4*)(out + (size_t)b * DD);
#pragma unroll 2
    for (int k = 0; k < 8; ++k) {
        const int v = k * 256 + t;
        float f[EFF + 3];
#pragma unroll
        for (int q = 0; q < 5; ++q) {
            float4 val = xr[(v - 2 + q) & (DF4 - 1)];
            f[q * 4 + 0] = val.x; f[q * 4 + 1] = val.y;
            f[q * 4 + 2] = val.z; f[q * 4 + 3] = val.w;
        }
        float oc[4];
#pragma unroll
        for (int c = 0; c < 4; ++c) {
            float s = 0.f;
#pragma unroll
            for (int m = 0; m < EFF; ++m) s += e[m] * f[c + m];
            oc[c] = s;
        }
        float4 o;
        o.x = oc[0]; o.y = oc[1]; o.z = oc[2]; o.w = oc[3];
        outr[v] = o;
    }
}

// ---------------------------------------------------------------------------
extern "C" void kernel_launch(void* const* d_in, const int* in_sizes, int n_in,
                              void* d_out, int out_size, void* d_ws, size_t ws_size,
                              hipStream_t stream) {
    const float* x       = (const float*)d_in[0];
    const int*   g       = (const int*)d_in[1];
    const float* kernels = (const float*)d_in[2];
    float*       out     = (float*)d_out;

    const size_t need = (size_t)(WS_OFF + BB * EPAD) * sizeof(float);
    if (ws_size >= need) {
        float* wsE = (float*)d_ws + WS_OFF;
        k_compose<<<BB / 256, 256, 0, stream>>>(g, kernels, wsE);
        k_conv_direct<<<BB, 256, 0, stream>>>(x, wsE, out);
    } else {
        int* ws = (int*)d_ws;
        k_max_it<<<1, 256, 0, stream>>>(g, ws);
        k_conv_fb<<<BB, 256, 0, stream>>>(x, g, kernels, ws, out);
    }
}

// Round 3
// 240.133 us; speedup vs baseline: 1.1555x; 1.1555x over previous
//
#include <hip/hip_runtime.h>

// Problem constants (match reference)
#define BB 4096
#define DD 8192
#define KK 5
#define GS 40
#define MAXIT 3
#define EFF 17              // 4*(KK-1)+1 composed taps
#define CHUNK 2048          // floats per block
#define C4 (CHUNK/4)        // 512 f4 per chunk
#define DF4 (DD/4)          // 2048 f4 per row
#define TPB 128             // threads per conv block (2 waves -> 16 blocks/CU)
#define EPAD 20             // padded per-row composed-kernel stride (floats, 5 f4)
#define WS_OFF 64           // float offset of E table inside ws (keeps ws[0] free)

typedef float vf4 __attribute__((ext_vector_type(4)));

__device__ __forceinline__ int iabs(int a) { return a < 0 ? -a : a; }

// Direct global->LDS DMA, 16 bytes per lane. LDS dest must be linear
// (wave-uniform base + lane*16); global src may be per-lane arbitrary.
__device__ __forceinline__ void gload_lds16(const float4* g, float4* l) {
    __builtin_amdgcn_global_load_lds(
        (const __attribute__((address_space(1))) void*)g,
        (__attribute__((address_space(3))) void*)l, 16, 0, 0);
}

// Compose e (length LEN) with a 5-tap kernel -> length LEN+4.
// LEN is a template parameter: all indices compile-time constant -> stays in VGPRs.
template<int LEN>
__device__ __forceinline__ void compose5(float* e, const float* k5) {
    float ne[LEN + KK - 1];
#pragma unroll
    for (int m = 0; m < LEN + KK - 1; ++m) ne[m] = 0.f;
#pragma unroll
    for (int m = 0; m < LEN; ++m)
#pragma unroll
        for (int j = 0; j < KK; ++j) ne[m + j] += e[m] * k5[j];
#pragma unroll
    for (int m = 0; m < LEN + KK - 1; ++m) e[m] = ne[m];
}

__device__ __forceinline__ void pick5(int i, int iters, int max_it,
                                      const float* maxk, const float* idk,
                                      float* k5) {
#pragma unroll
    for (int j = 0; j < KK; ++j)
        k5[j] = (i < iters) ? maxk[j]
              : ((i < max_it) ? idk[j] : ((j == (KK - 1) / 2) ? 1.f : 0.f));
}

// ---------------------------------------------------------------------------
// Kernel A (16 blocks x 256): batch max + per-row composed 17-tap kernel.
// Verified in rounds 1-2. Writes E[4096][EPAD] to ws.
// ---------------------------------------------------------------------------
__global__ __launch_bounds__(256) void k_compose(const int* __restrict__ g,
                                                 const float* __restrict__ kernels,
                                                 float* __restrict__ wsE) {
    __shared__ int red[256];
    const int t = threadIdx.x;

    const int4* g4 = (const int4*)g;
    int m = 0;
    for (int i = t; i < BB / 4; i += 256) {
        int4 v = g4[i];
        m = max(m, max(max(iabs(v.x), iabs(v.y)), max(iabs(v.z), iabs(v.w))));
    }
    red[t] = m;
    __syncthreads();
    for (int s = 128; s > 0; s >>= 1) {
        if (t < s) red[t] = max(red[t], red[t + s]);
        __syncthreads();
    }
    const int max_it = red[0] / GS;

    const int r  = blockIdx.x * 256 + t;     // row, 16*256 = 4096
    const int gv = g[r];
    const int sign  = gv > 0 ? 1 : (gv < 0 ? -1 : 0);
    const int a     = iabs(gv);
    const int iters = a / GS;
    const int rem   = a % GS;

    const float* mk = kernels + (size_t)(sign * GS + GS) * KK;
    const float* ik = kernels + (size_t)GS * KK;
    const float* fk = kernels + (size_t)(rem * sign + GS) * KK;
    float maxk[KK], idk[KK], fink[KK];
#pragma unroll
    for (int j = 0; j < KK; ++j) { maxk[j] = mk[j]; idk[j] = ik[j]; fink[j] = fk[j]; }

    float e[EPAD];
#pragma unroll
    for (int q = 0; q < EPAD; ++q) e[q] = 0.f;
    e[0] = 1.f;

    float k5[KK];
    pick5(0, iters, max_it, maxk, idk, k5); compose5<1>(e, k5);
    pick5(1, iters, max_it, maxk, idk, k5); compose5<5>(e, k5);
    pick5(2, iters, max_it, maxk, idk, k5); compose5<9>(e, k5);
    compose5<13>(e, fink);                   // e[0..16] final, e[17..19] = 0

    vf4* dst = (vf4*)(wsE + (size_t)r * EPAD);
    vf4 o0; o0.x = e[0];  o0.y = e[1];  o0.z = e[2];  o0.w = e[3];
    vf4 o1; o1.x = e[4];  o1.y = e[5];  o1.z = e[6];  o1.w = e[7];
    vf4 o2; o2.x = e[8];  o2.y = e[9];  o2.z = e[10]; o2.w = e[11];
    vf4 o3; o3.x = e[12]; o3.y = e[13]; o3.z = e[14]; o3.w = e[15];
    vf4 o4; o4.x = e[16]; o4.y = e[17]; o4.z = e[18]; o4.w = e[19];
    dst[0] = o0; dst[1] = o1; dst[2] = o2; dst[3] = o3; dst[4] = o4;
}

// ---------------------------------------------------------------------------
// Kernel B: LDS-staged stream conv (best-known structure, refined).
// 128 threads/block (2 waves) -> 16 independent blocks/CU at full 32-wave
// occupancy: barrier-drain bubbles are 2-wave-granular and hidden by the
// other 15 resident blocks. Whole 516-f4 window (chunk + 2 halo f4 each
// side) staged via global_load_lds DMA (linear LDS dest, per-lane wrapped
// global src); tail 4 f4 via plain load+ds_write by 4 threads. Compute:
// 4 interleaved f4 outputs/thread (16B lane stride = free 2-way LDS
// conflict), 272 FMAs, NT f4 stores.
// ---------------------------------------------------------------------------
__global__ __launch_bounds__(TPB) void k_conv_pre(const float* __restrict__ x,
                                                  const float* __restrict__ wsE,
                                                  float* __restrict__ out) {
    __shared__ float4 ldsw[C4 + 4];          // window = x[4*(c0f4-2) .. ], 516 f4

    const int bi   = blockIdx.x;
    const int b    = bi >> 2;                // row
    const int ch   = bi & 3;                 // chunk within row
    const int t    = threadIdx.x;
    const int c0f4 = ch * C4;

    const float4* xr = (const float4*)(x + (size_t)b * DD);

    // --- stage window [c0f4-2 .. c0f4+513] direct to LDS, fire-and-forget ---
#pragma unroll
    for (int s = 0; s < 4; ++s) {
        const int wi = s * TPB + t;          // window f4 idx 0..511
        gload_lds16(xr + ((c0f4 - 2 + wi) & (DF4 - 1)), &ldsw[wi]);
    }
    if (t < 4) {                             // tail window f4 512..515
        const int wi = 512 + t;
        ldsw[wi] = xr[(c0f4 - 2 + wi) & (DF4 - 1)];
    }

    // --- block-uniform composed kernel: 5 f4, L2-hot, overlaps staging ---
    const float4* ev = (const float4*)(wsE + (size_t)b * EPAD);
    float4 e0 = ev[0], e1 = ev[1], e2 = ev[2], e3 = ev[3], e4 = ev[4];
    float e[EFF] = { e0.x, e0.y, e0.z, e0.w,
                     e1.x, e1.y, e1.z, e1.w,
                     e2.x, e2.y, e2.z, e2.w,
                     e3.x, e3.y, e3.z, e3.w,
                     e4.x };

    __syncthreads();                         // drains DMA (vmcnt) + ds_write

    // --- compute: 4 f4 outputs per thread, interleaved ---
    vf4* outr = (vf4*)(out + (size_t)b * DD);
#pragma unroll
    for (int s = 0; s < 4; ++s) {
        const int v = s * TPB + t;           // output f4 idx within chunk [0,512)
        float f[EFF + 3];                    // x[4v-8 .. 4v+11] (window offset: v+q)
#pragma unroll
        for (int q = 0; q < 5; ++q) {
            float4 val = ldsw[v + q];        // window starts at chunk-2 f4
            f[q * 4 + 0] = val.x; f[q * 4 + 1] = val.y;
            f[q * 4 + 2] = val.z; f[q * 4 + 3] = val.w;
        }
        float oc[4];
#pragma unroll
        for (int c = 0; c < 4; ++c) {
            float s2 = 0.f;
#pragma unroll
            for (int m = 0; m < EFF; ++m) s2 += e[m] * f[c + m];
            oc[c] = s2;
        }
        vf4 o;
        o.x = oc[0]; o.y = oc[1]; o.z = oc[2]; o.w = oc[3];
        __builtin_nontemporal_store(o, outr + c0f4 + v);
    }
}

// ---------------------------------------------------------------------------
// Fallback path (ws too small): self-contained direct kernels (never taken
// on this harness -- ws has been large enough in all rounds).
// ---------------------------------------------------------------------------
__global__ __launch_bounds__(256) void k_max_it(const int* __restrict__ g,
                                                int* __restrict__ ws) {
    __shared__ int red[256];
    int t = threadIdx.x;
    int m = 0;
    for (int i = t; i < BB; i += 256) m = max(m, iabs(g[i]));
    red[t] = m;
    __syncthreads();
    for (int s = 128; s > 0; s >>= 1) {
        if (t < s) red[t] = max(red[t], red[t + s]);
        __syncthreads();
    }
    if (t == 0) ws[0] = red[0] / GS;
}

__global__ __launch_bounds__(256) void k_conv_fb(const float* __restrict__ x,
                                                 const int* __restrict__ g,
                                                 const float* __restrict__ kernels,
                                                 const int* __restrict__ ws,
                                                 float* __restrict__ out) {
    const int b = blockIdx.x;
    const int t = threadIdx.x;

    const int gv    = g[b];
    const int sign  = gv > 0 ? 1 : (gv < 0 ? -1 : 0);
    const int a     = iabs(gv);
    const int iters = a / GS;
    const int rem   = a % GS;
    const int max_it = ws[0];

    float maxk[KK], idk[KK], fink[KK];
    const float* mk = kernels + (size_t)(sign * GS + GS) * KK;
    const float* ik = kernels + (size_t)GS * KK;
    const float* fk = kernels + (size_t)(rem * sign + GS) * KK;
#pragma unroll
    for (int j = 0; j < KK; ++j) { maxk[j] = mk[j]; idk[j] = ik[j]; fink[j] = fk[j]; }

    float e[EPAD];
#pragma unroll
    for (int q = 0; q < EPAD; ++q) e[q] = 0.f;
    e[0] = 1.f;
    float k5[KK];
    pick5(0, iters, max_it, maxk, idk, k5); compose5<1>(e, k5);
    pick5(1, iters, max_it, maxk, idk, k5); compose5<5>(e, k5);
    pick5(2, iters, max_it, maxk, idk, k5); compose5<9>(e, k5);
    compose5<13>(e, fink);

    const float4* xr   = (const float4*)(x + (size_t)b * DD);
    float4*       outr = (float4*)(out + (size_t)b * DD);
#pragma unroll 2
    for (int k = 0; k < 8; ++k) {
        const int v = k * 256 + t;
        float f[EFF + 3];
#pragma unroll
        for (int q = 0; q < 5; ++q) {
            float4 val = xr[(v - 2 + q) & (DF4 - 1)];
            f[q * 4 + 0] = val.x; f[q * 4 + 1] = val.y;
            f[q * 4 + 2] = val.z; f[q * 4 + 3] = val.w;
        }
        float oc[4];
#pragma unroll
        for (int c = 0; c < 4; ++c) {
            float s = 0.f;
#pragma unroll
            for (int m = 0; m < EFF; ++m) s += e[m] * f[c + m];
            oc[c] = s;
        }
        float4 o;
        o.x = oc[0]; o.y = oc[1]; o.z = oc[2]; o.w = oc[3];
        outr[v] = o;
    }
}

// ---------------------------------------------------------------------------
extern "C" void kernel_launch(void* const* d_in, const int* in_sizes, int n_in,
                              void* d_out, int out_size, void* d_ws, size_t ws_size,
                              hipStream_t stream) {
    const float* x       = (const float*)d_in[0];
    const int*   g       = (const int*)d_in[1];
    const float* kernels = (const float*)d_in[2];
    float*       out     = (float*)d_out;

    const size_t need = (size_t)(WS_OFF + BB * EPAD) * sizeof(float);
    if (ws_size >= need) {
        float* wsE = (float*)d_ws + WS_OFF;
        k_compose<<<BB / 256, 256, 0, stream>>>(g, kernels, wsE);
        k_conv_pre<<<BB * (DD / CHUNK), TPB, 0, stream>>>(x, wsE, out);
    } else {
        int* ws = (int*)d_ws;
        k_max_it<<<1, 256, 0, stream>>>(g, ws);
        k_conv_fb<<<BB, 256, 0, stream>>>(x, g, kernels, ws, out);
    }
}

// Round 4
// 237.346 us; speedup vs baseline: 1.1690x; 1.0117x over previous
//
#include <hip/hip_runtime.h>

// Problem constants (match reference)
#define BB 4096
#define DD 8192
#define KK 5
#define GS 40
#define MAXIT 3
#define EFF 17              // 4*(KK-1)+1 composed taps
#define DF4 (DD/4)          // 2048 f4 per row
#define EPAD 20             // padded per-row composed-kernel stride (floats, 5 f4)
#define WS_OFF 64           // float offset of E table inside ws (keeps ws[0] free)

typedef float vf4 __attribute__((ext_vector_type(4)));

__device__ __forceinline__ int iabs(int a) { return a < 0 ? -a : a; }

// Compose e (length LEN) with a 5-tap kernel -> length LEN+4.
// LEN template param: all indices compile-time constant -> stays in VGPRs.
template<int LEN>
__device__ __forceinline__ void compose5(float* e, const float* k5) {
    float ne[LEN + KK - 1];
#pragma unroll
    for (int m = 0; m < LEN + KK - 1; ++m) ne[m] = 0.f;
#pragma unroll
    for (int m = 0; m < LEN; ++m)
#pragma unroll
        for (int j = 0; j < KK; ++j) ne[m + j] += e[m] * k5[j];
#pragma unroll
    for (int m = 0; m < LEN + KK - 1; ++m) e[m] = ne[m];
}

__device__ __forceinline__ void pick5(int i, int iters, int max_it,
                                      const float* maxk, const float* idk,
                                      float* k5) {
#pragma unroll
    for (int j = 0; j < KK; ++j)
        k5[j] = (i < iters) ? maxk[j]
              : ((i < max_it) ? idk[j] : ((j == (KK - 1) / 2) ? 1.f : 0.f));
}

// ---------------------------------------------------------------------------
// Kernel A (16 blocks x 256): batch max + per-row composed 17-tap kernel.
// Verified rounds 1-3. Writes E[4096][EPAD] to ws.
// ---------------------------------------------------------------------------
__global__ __launch_bounds__(256) void k_compose(const int* __restrict__ g,
                                                 const float* __restrict__ kernels,
                                                 float* __restrict__ wsE) {
    __shared__ int red[256];
    const int t = threadIdx.x;

    const int4* g4 = (const int4*)g;
    int m = 0;
    for (int i = t; i < BB / 4; i += 256) {
        int4 v = g4[i];
        m = max(m, max(max(iabs(v.x), iabs(v.y)), max(iabs(v.z), iabs(v.w))));
    }
    red[t] = m;
    __syncthreads();
    for (int s = 128; s > 0; s >>= 1) {
        if (t < s) red[t] = max(red[t], red[t + s]);
        __syncthreads();
    }
    const int max_it = red[0] / GS;

    const int r  = blockIdx.x * 256 + t;     // row, 16*256 = 4096
    const int gv = g[r];
    const int sign  = gv > 0 ? 1 : (gv < 0 ? -1 : 0);
    const int a     = iabs(gv);
    const int iters = a / GS;
    const int rem   = a % GS;

    const float* mk = kernels + (size_t)(sign * GS + GS) * KK;
    const float* ik = kernels + (size_t)GS * KK;
    const float* fk = kernels + (size_t)(rem * sign + GS) * KK;
    float maxk[KK], idk[KK], fink[KK];
#pragma unroll
    for (int j = 0; j < KK; ++j) { maxk[j] = mk[j]; idk[j] = ik[j]; fink[j] = fk[j]; }

    float e[EPAD];
#pragma unroll
    for (int q = 0; q < EPAD; ++q) e[q] = 0.f;
    e[0] = 1.f;

    float k5[KK];
    pick5(0, iters, max_it, maxk, idk, k5); compose5<1>(e, k5);
    pick5(1, iters, max_it, maxk, idk, k5); compose5<5>(e, k5);
    pick5(2, iters, max_it, maxk, idk, k5); compose5<9>(e, k5);
    compose5<13>(e, fink);                   // e[0..16] final, e[17..19] = 0

    vf4* dst = (vf4*)(wsE + (size_t)r * EPAD);
    vf4 o0; o0.x = e[0];  o0.y = e[1];  o0.z = e[2];  o0.w = e[3];
    vf4 o1; o1.x = e[4];  o1.y = e[5];  o1.z = e[6];  o1.w = e[7];
    vf4 o2; o2.x = e[8];  o2.y = e[9];  o2.z = e[10]; o2.w = e[11];
    vf4 o3; o3.x = e[12]; o3.y = e[13]; o3.z = e[14]; o3.w = e[15];
    vf4 o4; o4.x = e[16]; o4.y = e[17]; o4.z = e[18]; o4.w = e[19];
    dst[0] = o0; dst[1] = o1; dst[2] = o2; dst[3] = o3; dst[4] = o4;
}

// ---------------------------------------------------------------------------
// Kernel B: BARRIER-FREE wave-private conv.
// 256 threads = 4 waves/block, 8 blocks/CU (wave-capped, forced via
// __launch_bounds__(256,8)). Each wave stages its own 132-f4 window
// (128 outputs + 2 halo f4 each side) into a wave-private LDS region:
// no __syncthreads anywhere -> no block-wide vmcnt(0) drain bubbles;
// waves are independent latency-hiding pipelines. Lanes keep their two
// staged f4 in registers, so each of the 2 output f4s needs only 4 LDS
// reads (was 5). In-wave LDS RAW ordered by lgkmcnt (DS pipe in-order).
// ---------------------------------------------------------------------------
__global__ __launch_bounds__(256, 8) void k_conv_wave(const float* __restrict__ x,
                                                      const float* __restrict__ wsE,
                                                      float* __restrict__ out) {
    __shared__ float4 win[4][132];           // per-wave window, 8448 B/block

    const int bi  = blockIdx.x;
    const int b   = bi >> 2;                 // row
    const int ch  = bi & 3;                  // 512-f4 chunk within row
    const int t   = threadIdx.x;
    const int w   = t >> 6;                  // wave id 0..3
    const int l   = t & 63;                  // lane
    const int wf0 = ch * 512 + w * 128;      // wave's first output f4 (row-rel)

    const float4* xr = (const float4*)(x + (size_t)b * DD);

    // --- stage: window [wf0-2 .. wf0+129], values also kept in regs ---
    float4 r0 = xr[(wf0 -  2 + l) & (DF4 - 1)];
    float4 r1 = xr[(wf0 + 62 + l) & (DF4 - 1)];
    float4 rt;
    if (l < 4) rt = xr[(wf0 + 126 + l) & (DF4 - 1)];

    // block-uniform composed kernel (uniform addr -> scalarizable)
    const float4* ev = (const float4*)(wsE + (size_t)b * EPAD);
    float4 e0 = ev[0], e1 = ev[1], e2 = ev[2], e3 = ev[3], e4 = ev[4];
    float e[EFF] = { e0.x, e0.y, e0.z, e0.w,
                     e1.x, e1.y, e1.z, e1.w,
                     e2.x, e2.y, e2.z, e2.w,
                     e3.x, e3.y, e3.z, e3.w,
                     e4.x };

    win[w][l]      = r0;                     // win[i] == f4 (wf0-2+i)
    win[w][64 + l] = r1;
    if (l < 4) win[w][128 + l] = rt;

    // in-wave RAW fence: ds_writes complete before cross-lane ds_reads
    asm volatile("s_waitcnt lgkmcnt(0)" ::: "memory");

    vf4* outr = (vf4*)(out + (size_t)b * DD);

    // --- output 0: f4 at wf0 + l ---
    {
        float f[EFF + 3];
        f[0] = r0.x; f[1] = r0.y; f[2] = r0.z; f[3] = r0.w;
#pragma unroll
        for (int q = 1; q < 5; ++q) {
            float4 val = win[w][l + q];
            f[q * 4 + 0] = val.x; f[q * 4 + 1] = val.y;
            f[q * 4 + 2] = val.z; f[q * 4 + 3] = val.w;
        }
        float oc[4];
#pragma unroll
        for (int c = 0; c < 4; ++c) {
            float s = 0.f;
#pragma unroll
            for (int m = 0; m < EFF; ++m) s += e[m] * f[c + m];
            oc[c] = s;
        }
        vf4 o; o.x = oc[0]; o.y = oc[1]; o.z = oc[2]; o.w = oc[3];
        __builtin_nontemporal_store(o, outr + wf0 + l);
    }

    // --- output 1: f4 at wf0 + 64 + l ---
    {
        float f[EFF + 3];
        f[0] = r1.x; f[1] = r1.y; f[2] = r1.z; f[3] = r1.w;
#pragma unroll
        for (int q = 1; q < 5; ++q) {
            float4 val = win[w][64 + l + q];
            f[q * 4 + 0] = val.x; f[q * 4 + 1] = val.y;
            f[q * 4 + 2] = val.z; f[q * 4 + 3] = val.w;
        }
        float oc[4];
#pragma unroll
        for (int c = 0; c < 4; ++c) {
            float s = 0.f;
#pragma unroll
            for (int m = 0; m < EFF; ++m) s += e[m] * f[c + m];
            oc[c] = s;
        }
        vf4 o; o.x = oc[0]; o.y = oc[1]; o.z = oc[2]; o.w = oc[3];
        __builtin_nontemporal_store(o, outr + wf0 + 64 + l);
    }
}

// ---------------------------------------------------------------------------
// Fallback path (ws too small): self-contained direct kernels.
// ---------------------------------------------------------------------------
__global__ __launch_bounds__(256) void k_max_it(const int* __restrict__ g,
                                                int* __restrict__ ws) {
    __shared__ int red[256];
    int t = threadIdx.x;
    int m = 0;
    for (int i = t; i < BB; i += 256) m = max(m, iabs(g[i]));
    red[t] = m;
    __syncthreads();
    for (int s = 128; s > 0; s >>= 1) {
        if (t < s) red[t] = max(red[t], red[t + s]);
        __syncthreads();
    }
    if (t == 0) ws[0] = red[0] / GS;
}

__global__ __launch_bounds__(256) void k_conv_fb(const float* __restrict__ x,
                                                 const int* __restrict__ g,
                                                 const float* __restrict__ kernels,
                                                 const int* __restrict__ ws,
                                                 float* __restrict__ out) {
    const int b = blockIdx.x;
    const int t = threadIdx.x;

    const int gv    = g[b];
    const int sign  = gv > 0 ? 1 : (gv < 0 ? -1 : 0);
    const int a     = iabs(gv);
    const int iters = a / GS;
    const int rem   = a % GS;
    const int max_it = ws[0];

    float maxk[KK], idk[KK], fink[KK];
    const float* mk = kernels + (size_t)(sign * GS + GS) * KK;
    const float* ik = kernels + (size_t)GS * KK;
    const float* fk = kernels + (size_t)(rem * sign + GS) * KK;
#pragma unroll
    for (int j = 0; j < KK; ++j) { maxk[j] = mk[j]; idk[j] = ik[j]; fink[j] = fk[j]; }

    float e[EPAD];
#pragma unroll
    for (int q = 0; q < EPAD; ++q) e[q] = 0.f;
    e[0] = 1.f;
    float k5[KK];
    pick5(0, iters, max_it, maxk, idk, k5); compose5<1>(e, k5);
    pick5(1, iters, max_it, maxk, idk, k5); compose5<5>(e, k5);
    pick5(2, iters, max_it, maxk, idk, k5); compose5<9>(e, k5);
    compose5<13>(e, fink);

    const float4* xr   = (const float4*)(x + (size_t)b * DD);
    float4*       outr = (float4*)(out + (size_t)b * DD);
#pragma unroll 2
    for (int k = 0; k < 8; ++k) {
        const int v = k * 256 + t;
        float f[EFF + 3];
#pragma unroll
        for (int q = 0; q < 5; ++q) {
            float4 val = xr[(v - 2 + q) & (DF4 - 1)];
            f[q * 4 + 0] = val.x; f[q * 4 + 1] = val.y;
            f[q * 4 + 2] = val.z; f[q * 4 + 3] = val.w;
        }
        float oc[4];
#pragma unroll
        for (int c = 0; c < 4; ++c) {
            float s = 0.f;
#pragma unroll
            for (int m = 0; m < EFF; ++m) s += e[m] * f[c + m];
            oc[c] = s;
        }
        float4 o;
        o.x = oc[0]; o.y = oc[1]; o.z = oc[2]; o.w = oc[3];
        outr[v] = o;
    }
}

// ---------------------------------------------------------------------------
extern "C" void kernel_launch(void* const* d_in, const int* in_sizes, int n_in,
                              void* d_out, int out_size, void* d_ws, size_t ws_size,
                              hipStream_t stream) {
    const float* x       = (const float*)d_in[0];
    const int*   g       = (const int*)d_in[1];
    const float* kernels = (const float*)d_in[2];
    float*       out     = (float*)d_out;

    const size_t need = (size_t)(WS_OFF + BB * EPAD) * sizeof(float);
    if (ws_size >= need) {
        float* wsE = (float*)d_ws + WS_OFF;
        k_compose<<<BB / 256, 256, 0, stream>>>(g, kernels, wsE);
        k_conv_wave<<<BB * 4, 256, 0, stream>>>(x, wsE, out);
    } else {
        int* ws = (int*)d_ws;
        k_max_it<<<1, 256, 0, stream>>>(g, ws);
        k_conv_fb<<<BB, 256, 0, stream>>>(x, g, kernels, ws, out);
    }
}

// Round 6
// 235.227 us; speedup vs baseline: 1.1796x; 1.0090x over previous
//
#include <hip/hip_runtime.h>

// Problem constants (match reference)
#define BB 4096
#define DD 8192
#define KK 5
#define GS 40
#define MAXIT 3
#define EFF 17              // 4*(KK-1)+1 composed taps
#define DF4 (DD/4)          // 2048 f4 per row
#define EPAD 20             // padded per-row composed-kernel stride (floats, 5 f4)
#define WS_OFF 64           // float offset of E table inside ws (keeps ws[0] free)

typedef float vf4 __attribute__((ext_vector_type(4)));

__device__ __forceinline__ int iabs(int a) { return a < 0 ? -a : a; }

// Compose e (length LEN) with a 5-tap kernel -> length LEN+4.
// LEN template param: all indices compile-time constant -> stays in VGPRs.
template<int LEN>
__device__ __forceinline__ void compose5(float* e, const float* k5) {
    float ne[LEN + KK - 1];
#pragma unroll
    for (int m = 0; m < LEN + KK - 1; ++m) ne[m] = 0.f;
#pragma unroll
    for (int m = 0; m < LEN; ++m)
#pragma unroll
        for (int j = 0; j < KK; ++j) ne[m + j] += e[m] * k5[j];
#pragma unroll
    for (int m = 0; m < LEN + KK - 1; ++m) e[m] = ne[m];
}

__device__ __forceinline__ void pick5(int i, int iters, int max_it,
                                      const float* maxk, const float* idk,
                                      float* k5) {
#pragma unroll
    for (int j = 0; j < KK; ++j)
        k5[j] = (i < iters) ? maxk[j]
              : ((i < max_it) ? idk[j] : ((j == (KK - 1) / 2) ? 1.f : 0.f));
}

// ---------------------------------------------------------------------------
// Kernel A (16 blocks x 256): batch max + per-row composed 17-tap kernel.
// Verified rounds 1-4. Writes E[4096][EPAD] to ws.
// ---------------------------------------------------------------------------
__global__ __launch_bounds__(256) void k_compose(const int* __restrict__ g,
                                                 const float* __restrict__ kernels,
                                                 float* __restrict__ wsE) {
    __shared__ int red[256];
    const int t = threadIdx.x;

    const int4* g4 = (const int4*)g;
    int m = 0;
    for (int i = t; i < BB / 4; i += 256) {
        int4 v = g4[i];
        m = max(m, max(max(iabs(v.x), iabs(v.y)), max(iabs(v.z), iabs(v.w))));
    }
    red[t] = m;
    __syncthreads();
    for (int s = 128; s > 0; s >>= 1) {
        if (t < s) red[t] = max(red[t], red[t + s]);
        __syncthreads();
    }
    const int max_it = red[0] / GS;

    const int r  = blockIdx.x * 256 + t;     // row, 16*256 = 4096
    const int gv = g[r];
    const int sign  = gv > 0 ? 1 : (gv < 0 ? -1 : 0);
    const int a     = iabs(gv);
    const int iters = a / GS;
    const int rem   = a % GS;

    const float* mk = kernels + (size_t)(sign * GS + GS) * KK;
    const float* ik = kernels + (size_t)GS * KK;
    const float* fk = kernels + (size_t)(rem * sign + GS) * KK;
    float maxk[KK], idk[KK], fink[KK];
#pragma unroll
    for (int j = 0; j < KK; ++j) { maxk[j] = mk[j]; idk[j] = ik[j]; fink[j] = fk[j]; }

    float e[EPAD];
#pragma unroll
    for (int q = 0; q < EPAD; ++q) e[q] = 0.f;
    e[0] = 1.f;

    float k5[KK];
    pick5(0, iters, max_it, maxk, idk, k5); compose5<1>(e, k5);
    pick5(1, iters, max_it, maxk, idk, k5); compose5<5>(e, k5);
    pick5(2, iters, max_it, maxk, idk, k5); compose5<9>(e, k5);
    compose5<13>(e, fink);                   // e[0..16] final, e[17..19] = 0

    vf4* dst = (vf4*)(wsE + (size_t)r * EPAD);
    vf4 o0; o0.x = e[0];  o0.y = e[1];  o0.z = e[2];  o0.w = e[3];
    vf4 o1; o1.x = e[4];  o1.y = e[5];  o1.z = e[6];  o1.w = e[7];
    vf4 o2; o2.x = e[8];  o2.y = e[9];  o2.z = e[10]; o2.w = e[11];
    vf4 o3; o3.x = e[12]; o3.y = e[13]; o3.z = e[14]; o3.w = e[15];
    vf4 o4; o4.x = e[16]; o4.y = e[17]; o4.z = e[18]; o4.w = e[19];
    dst[0] = o0; dst[1] = o1; dst[2] = o2; dst[3] = o3; dst[4] = o4;
}

// ---------------------------------------------------------------------------
// Kernel B: BARRIER-FREE wave-private conv (identical to Round 4) with ONE
// change: plain f4 stores instead of __builtin_nontemporal_store. A/B test:
// all NT-store variants plateaued at ~75 us (2.7 TB/s effective) while the
// same machine sustains 6.8 TB/s on fills; NT bypasses L2 and is the one
// untested common factor. Everything else byte-identical to R4.
// ---------------------------------------------------------------------------
__global__ __launch_bounds__(256, 8) void k_conv_wave(const float* __restrict__ x,
                                                      const float* __restrict__ wsE,
                                                      float* __restrict__ out) {
    __shared__ float4 win[4][132];           // per-wave window, 8448 B/block

    const int bi  = blockIdx.x;
    const int b   = bi >> 2;                 // row
    const int ch  = bi & 3;                  // 512-f4 chunk within row
    const int t   = threadIdx.x;
    const int w   = t >> 6;                  // wave id 0..3
    const int l   = t & 63;                  // lane
    const int wf0 = ch * 512 + w * 128;      // wave's first output f4 (row-rel)

    const float4* xr = (const float4*)(x + (size_t)b * DD);

    // --- stage: window [wf0-2 .. wf0+129], values also kept in regs ---
    float4 r0 = xr[(wf0 -  2 + l) & (DF4 - 1)];
    float4 r1 = xr[(wf0 + 62 + l) & (DF4 - 1)];
    float4 rt;
    if (l < 4) rt = xr[(wf0 + 126 + l) & (DF4 - 1)];

    // block-uniform composed kernel (uniform addr -> scalarizable)
    const float4* ev = (const float4*)(wsE + (size_t)b * EPAD);
    float4 e0 = ev[0], e1 = ev[1], e2 = ev[2], e3 = ev[3], e4 = ev[4];
    float e[EFF] = { e0.x, e0.y, e0.z, e0.w,
                     e1.x, e1.y, e1.z, e1.w,
                     e2.x, e2.y, e2.z, e2.w,
                     e3.x, e3.y, e3.z, e3.w,
                     e4.x };

    win[w][l]      = r0;                     // win[i] == f4 (wf0-2+i)
    win[w][64 + l] = r1;
    if (l < 4) win[w][128 + l] = rt;

    // in-wave RAW fence: ds_writes complete before cross-lane ds_reads
    asm volatile("s_waitcnt lgkmcnt(0)" ::: "memory");

    float4* outr = (float4*)(out + (size_t)b * DD);

    // --- output 0: f4 at wf0 + l ---
    {
        float f[EFF + 3];
        f[0] = r0.x; f[1] = r0.y; f[2] = r0.z; f[3] = r0.w;
#pragma unroll
        for (int q = 1; q < 5; ++q) {
            float4 val = win[w][l + q];
            f[q * 4 + 0] = val.x; f[q * 4 + 1] = val.y;
            f[q * 4 + 2] = val.z; f[q * 4 + 3] = val.w;
        }
        float oc[4];
#pragma unroll
        for (int c = 0; c < 4; ++c) {
            float s = 0.f;
#pragma unroll
            for (int m = 0; m < EFF; ++m) s += e[m] * f[c + m];
            oc[c] = s;
        }
        float4 o; o.x = oc[0]; o.y = oc[1]; o.z = oc[2]; o.w = oc[3];
        outr[wf0 + l] = o;                   // plain store (A/B vs R4's NT)
    }

    // --- output 1: f4 at wf0 + 64 + l ---
    {
        float f[EFF + 3];
        f[0] = r1.x; f[1] = r1.y; f[2] = r1.z; f[3] = r1.w;
#pragma unroll
        for (int q = 1; q < 5; ++q) {
            float4 val = win[w][64 + l + q];
            f[q * 4 + 0] = val.x; f[q * 4 + 1] = val.y;
            f[q * 4 + 2] = val.z; f[q * 4 + 3] = val.w;
        }
        float oc[4];
#pragma unroll
        for (int c = 0; c < 4; ++c) {
            float s = 0.f;
#pragma unroll
            for (int m = 0; m < EFF; ++m) s += e[m] * f[c + m];
            oc[c] = s;
        }
        float4 o; o.x = oc[0]; o.y = oc[1]; o.z = oc[2]; o.w = oc[3];
        outr[wf0 + 64 + l] = o;              // plain store (A/B vs R4's NT)
    }
}

// ---------------------------------------------------------------------------
// Fallback path (ws too small): self-contained direct kernels.
// ---------------------------------------------------------------------------
__global__ __launch_bounds__(256) void k_max_it(const int* __restrict__ g,
                                                int* __restrict__ ws) {
    __shared__ int red[256];
    int t = threadIdx.x;
    int m = 0;
    for (int i = t; i < BB; i += 256) m = max(m, iabs(g[i]));
    red[t] = m;
    __syncthreads();
    for (int s = 128; s > 0; s >>= 1) {
        if (t < s) red[t] = max(red[t], red[t + s]);
        __syncthreads();
    }
    if (t == 0) ws[0] = red[0] / GS;
}

__global__ __launch_bounds__(256) void k_conv_fb(const float* __restrict__ x,
                                                 const int* __restrict__ g,
                                                 const float* __restrict__ kernels,
                                                 const int* __restrict__ ws,
                                                 float* __restrict__ out) {
    const int b = blockIdx.x;
    const int t = threadIdx.x;

    const int gv    = g[b];
    const int sign  = gv > 0 ? 1 : (gv < 0 ? -1 : 0);
    const int a     = iabs(gv);
    const int iters = a / GS;
    const int rem   = a % GS;
    const int max_it = ws[0];

    float maxk[KK], idk[KK], fink[KK];
    const float* mk = kernels + (size_t)(sign * GS + GS) * KK;
    const float* ik = kernels + (size_t)GS * KK;
    const float* fk = kernels + (size_t)(rem * sign + GS) * KK;
#pragma unroll
    for (int j = 0; j < KK; ++j) { maxk[j] = mk[j]; idk[j] = ik[j]; fink[j] = fk[j]; }

    float e[EPAD];
#pragma unroll
    for (int q = 0; q < EPAD; ++q) e[q] = 0.f;
    e[0] = 1.f;
    float k5[KK];
    pick5(0, iters, max_it, maxk, idk, k5); compose5<1>(e, k5);
    pick5(1, iters, max_it, maxk, idk, k5); compose5<5>(e, k5);
    pick5(2, iters, max_it, maxk, idk, k5); compose5<9>(e, k5);
    compose5<13>(e, fink);

    const float4* xr   = (const float4*)(x + (size_t)b * DD);
    float4*       outr = (float4*)(out + (size_t)b * DD);
#pragma unroll 2
    for (int k = 0; k < 8; ++k) {
        const int v = k * 256 + t;
        float f[EFF + 3];
#pragma unroll
        for (int q = 0; q < 5; ++q) {
            float4 val = xr[(v - 2 + q) & (DF4 - 1)];
            f[q * 4 + 0] = val.x; f[q * 4 + 1] = val.y;
            f[q * 4 + 2] = val.z; f[q * 4 + 3] = val.w;
        }
        float oc[4];
#pragma unroll
        for (int c = 0; c < 4; ++c) {
            float s = 0.f;
#pragma unroll
            for (int m = 0; m < EFF; ++m) s += e[m] * f[c + m];
            oc[c] = s;
        }
        float4 o;
        o.x = oc[0]; o.y = oc[1]; o.z = oc[2]; o.w = oc[3];
        outr[v] = o;
    }
}

// ---------------------------------------------------------------------------
extern "C" void kernel_launch(void* const* d_in, const int* in_sizes, int n_in,
                              void* d_out, int out_size, void* d_ws, size_t ws_size,
                              hipStream_t stream) {
    const float* x       = (const float*)d_in[0];
    const int*   g       = (const int*)d_in[1];
    const float* kernels = (const float*)d_in[2];
    float*       out     = (float*)d_out;

    const size_t need = (size_t)(WS_OFF + BB * EPAD) * sizeof(float);
    if (ws_size >= need) {
        float* wsE = (float*)d_ws + WS_OFF;
        k_compose<<<BB / 256, 256, 0, stream>>>(g, kernels, wsE);
        k_conv_wave<<<BB * 4, 256, 0, stream>>>(x, wsE, out);
    } else {
        int* ws = (int*)d_ws;
        k_max_it<<<1, 256, 0, stream>>>(g, ws);
        k_conv_fb<<<BB, 256, 0, stream>>>(x, g, kernels, ws, out);
    }
}